// Round 10
// baseline (253.953 us; speedup 1.0000x reference)
//
#include <hip/hip_runtime.h>

// InitReduceConv: out[dst[e], :] += x[src[e], :]  (E=2M edges, D=64 fp32)
//
// Round-10: two-level counting sort replaces the 100k-way scattered bucket
// build (its 4B stores dirtied 98 MB of lines; uncombinable -- proven r6/r8).
//   A hist_kernel:      dst -> 782 coarse bins (128 rows each), LDS-staged
//   B scan_kernel:      exclusive scan -> exact bin offsets (no overflow)
//   C binscatter_kernel: per-block LDS sort of 16K edges by bin, then
//                        coalesced ~168B-run flush of (src,dst) pairs
//   D bingather_kernel:  per-bin: LDS counting-sort by local dst, then
//                        16-lane groups gather-sum x rows, write out once
//
// ws layout: [0, 4K)        hist    (nbins ints)
//            [16K, 20K)     bin_start (nbins+1 ints)
//            [32K, 36K)     bin_cursor (nbins ints)
//            [1M, 1M+16M)   binned  (E int2 pairs)

#define BIN_SHIFT 7
#define BIN_SIZE  (1 << BIN_SHIFT)     // 128 dst rows per bin
#define MAX_BINS  1024
#define CHUNK_C   16384                // edges staged per block in pass C
#define CHUNK_D   4096                 // edges per LDS chunk in pass D

typedef float vf4 __attribute__((ext_vector_type(4)));

// ---------- A: coarse histogram ----------
__global__ void hist_kernel(const int* __restrict__ dst, int* __restrict__ hist,
                            int E, int nbins) {
    __shared__ int lh[MAX_BINS];
    for (int i = threadIdx.x; i < nbins; i += blockDim.x) lh[i] = 0;
    __syncthreads();
    int stride = gridDim.x * blockDim.x;
    for (int e = blockIdx.x * blockDim.x + threadIdx.x; e < E; e += stride)
        atomicAdd(&lh[dst[e] >> BIN_SHIFT], 1);
    __syncthreads();
    for (int i = threadIdx.x; i < nbins; i += blockDim.x)
        if (lh[i]) atomicAdd(&hist[i], lh[i]);
}

// ---------- B: exclusive scan (single block, MAX_BINS threads) ----------
__global__ void scan_kernel(const int* __restrict__ hist,
                            int* __restrict__ bin_start,
                            int* __restrict__ bin_cursor, int nbins) {
    __shared__ int buf[MAX_BINS];
    int t = threadIdx.x;
    buf[t] = (t < nbins) ? hist[t] : 0;
    __syncthreads();
    for (int off = 1; off < MAX_BINS; off <<= 1) {
        int v = (t >= off) ? buf[t - off] : 0;
        __syncthreads();
        buf[t] += v;
        __syncthreads();
    }
    if (t < nbins) {
        int s = (t == 0) ? 0 : buf[t - 1];
        bin_start[t] = s;
        bin_cursor[t] = s;
    }
    if (t == 0) bin_start[nbins] = buf[MAX_BINS - 1];
}

// ---------- C: LDS-staged scatter into coarse bins ----------
__launch_bounds__(256, 1)
__global__ void binscatter_kernel(const int* __restrict__ bidx,
                                  int* __restrict__ bin_cursor,
                                  int2* __restrict__ binned,
                                  int E, int nbins) {
    __shared__ int2 stage[CHUNK_C];      // 128 KB
    __shared__ int cnt[MAX_BINS];        // hist -> later scatter cursor
    __shared__ int lstart[MAX_BINS];     // chunk-local exclusive starts
    __shared__ int gbase[MAX_BINS];      // global base per bin
    __shared__ int part[256];

    int base = blockIdx.x * CHUNK_C;
    int n = E - base; if (n > CHUNK_C) n = CHUNK_C;
    if (n <= 0) return;
    int t = threadIdx.x;

    for (int i = t; i < MAX_BINS; i += 256) cnt[i] = 0;
    __syncthreads();
    for (int i = t; i < n; i += 256)
        atomicAdd(&cnt[bidx[E + base + i] >> BIN_SHIFT], 1);
    __syncthreads();

    // 4-per-thread + Hillis-Steele(256) exclusive scan over MAX_BINS
    int b0 = t << 2;
    int c0 = cnt[b0], c1 = cnt[b0 + 1], c2 = cnt[b0 + 2], c3 = cnt[b0 + 3];
    part[t] = c0 + c1 + c2 + c3;
    __syncthreads();
    for (int off = 1; off < 256; off <<= 1) {
        int v = (t >= off) ? part[t - off] : 0;
        __syncthreads();
        part[t] += v;
        __syncthreads();
    }
    int ex = (t == 0) ? 0 : part[t - 1];
    lstart[b0]     = ex;
    lstart[b0 + 1] = ex + c0;
    lstart[b0 + 2] = ex + c0 + c1;
    lstart[b0 + 3] = ex + c0 + c1 + c2;
    __syncthreads();

    // allocate global runs; convert cnt into chunk-local scatter cursor
    for (int i = t; i < nbins; i += 256) {
        int next = (i + 1 < MAX_BINS) ? lstart[i + 1] : n;
        int cc = next - lstart[i];
        gbase[i] = cc ? atomicAdd(&bin_cursor[i], cc) : 0;
    }
    __syncthreads();
    for (int i = t; i < MAX_BINS; i += 256) cnt[i] = lstart[i];
    __syncthreads();

    // scatter pairs into LDS, grouped by bin
    for (int i = t; i < n; i += 256) {
        int s = bidx[base + i];
        int d = bidx[E + base + i];
        int pos = atomicAdd(&cnt[d >> BIN_SHIFT], 1);
        stage[pos] = make_int2(s, d);
    }
    __syncthreads();

    // coalesced flush: contiguous run per bin
    for (int i = t; i < n; i += 256) {
        int2 p = stage[i];
        int b = p.y >> BIN_SHIFT;
        binned[gbase[b] + (i - lstart[b])] = p;
    }
}

// ---------- D: per-bin LDS counting sort + fused gather-sum ----------
__global__ void bingather_kernel(const float4* __restrict__ x4,
                                 const int* __restrict__ bin_start,
                                 const int2* __restrict__ binned,
                                 float4* __restrict__ out4,
                                 int NOUT) {
    __shared__ int2 pairs[CHUNK_D];      // 32 KB
    __shared__ int ssrc[CHUNK_D];        // 16 KB
    __shared__ int cnt[BIN_SIZE];
    __shared__ int dstart[BIN_SIZE];
    __shared__ int dcur[BIN_SIZE];

    int bin = blockIdx.x;
    int estart = bin_start[bin], eend = bin_start[bin + 1];
    int t = threadIdx.x;
    int g = t >> 4, c = t & 15;          // 16 groups of 16 lanes

    float4 acc[8];
#pragma unroll
    for (int k = 0; k < 8; ++k) acc[k] = (float4){0.f, 0.f, 0.f, 0.f};

    for (int off = estart; off < eend; off += CHUNK_D) {
        int n = eend - off; if (n > CHUNK_D) n = CHUNK_D;

        if (t < BIN_SIZE) cnt[t] = 0;
        __syncthreads();
        for (int i = t; i < n; i += 256) {
            int2 p = binned[off + i];
            pairs[i] = p;
            atomicAdd(&cnt[p.y & (BIN_SIZE - 1)], 1);
        }
        __syncthreads();

        // exclusive scan of cnt -> dstart (Hillis-Steele on 128)
        if (t < BIN_SIZE) dstart[t] = cnt[t];
        __syncthreads();
        for (int o = 1; o < BIN_SIZE; o <<= 1) {
            int v = 0;
            if (t < BIN_SIZE && t >= o) v = dstart[t - o];
            __syncthreads();
            if (t < BIN_SIZE) dstart[t] += v;
            __syncthreads();
        }
        if (t < BIN_SIZE) {
            int ex = dstart[t] - cnt[t];
            dstart[t] = ex;
            dcur[t] = ex;
        }
        __syncthreads();

        // scatter srcs into dst-sorted order
        for (int i = t; i < n; i += 256) {
            int2 p = pairs[i];
            int pos = atomicAdd(&dcur[p.y & (BIN_SIZE - 1)], 1);
            ssrc[pos] = p.x;
        }
        __syncthreads();

        // gather: group g owns local dsts g, g+16, ..., g+112
#pragma unroll
        for (int k = 0; k < 8; ++k) {
            int d = g + (k << 4);
            int j0 = dstart[d];
            int j1 = j0 + cnt[d];
            float4 a0 = acc[k];
            float4 a1 = {0.f, 0.f, 0.f, 0.f};
            int j = j0;
            for (; j + 1 < j1; j += 2) {
                int s0 = ssrc[j], s1 = ssrc[j + 1];
                float4 v0 = x4[(size_t)s0 * 16 + c];
                float4 v1 = x4[(size_t)s1 * 16 + c];
                a0.x += v0.x; a0.y += v0.y; a0.z += v0.z; a0.w += v0.w;
                a1.x += v1.x; a1.y += v1.y; a1.z += v1.z; a1.w += v1.w;
            }
            if (j < j1) {
                float4 v = x4[(size_t)ssrc[j] * 16 + c];
                a0.x += v.x; a0.y += v.y; a0.z += v.z; a0.w += v.w;
            }
            acc[k].x = a0.x + a1.x; acc[k].y = a0.y + a1.y;
            acc[k].z = a0.z + a1.z; acc[k].w = a0.w + a1.w;
        }
        __syncthreads();   // LDS reuse in next chunk
    }

    int rowbase = bin << BIN_SHIFT;
#pragma unroll
    for (int k = 0; k < 8; ++k) {
        int row = rowbase + g + (k << 4);
        if (row < NOUT) out4[(size_t)row * 16 + c] = acc[k];
    }
}

// ---------- fallback: direct atomics ----------
__global__ void scatter_add_f4_kernel(const float4* __restrict__ x4,
                                      const int* __restrict__ bidx,
                                      float* __restrict__ out,
                                      int E) {
    int idx = blockIdx.x * blockDim.x + threadIdx.x;
    int total = E * 16;
    if (idx >= total) return;
    int e = idx >> 4;
    int c = idx & 15;
    int src = bidx[e];
    int dst = bidx[E + e];
    float4 v = x4[(size_t)src * 16 + c];
    float* o = out + (size_t)dst * 64 + (c << 2);
    atomicAdd(o + 0, v.x);
    atomicAdd(o + 1, v.y);
    atomicAdd(o + 2, v.z);
    atomicAdd(o + 3, v.w);
}

extern "C" void kernel_launch(void* const* d_in, const int* in_sizes, int n_in,
                              void* d_out, int out_size, void* d_ws, size_t ws_size,
                              hipStream_t stream) {
    const float* x = (const float*)d_in[0];
    const int* bidx = (const int*)d_in[1];
    float* out = (float*)d_out;

    const int E = in_sizes[1] / 2;          // 2,000,000
    const int NOUT = out_size / 64;         // 100,000
    const int nbins = (NOUT + BIN_SIZE - 1) >> BIN_SHIFT;   // 782

    const size_t BINNED_OFF = 1u << 20;
    size_t needed = BINNED_OFF + (size_t)E * sizeof(int2);

    if (nbins > MAX_BINS || (out_size % 64) != 0 || ws_size < needed) {
        hipMemsetAsync(d_out, 0, (size_t)out_size * sizeof(float), stream);
        int total = E * 16;
        scatter_add_f4_kernel<<<(total + 255) / 256, 256, 0, stream>>>(
            (const float4*)x, bidx, out, E);
        return;
    }

    char* ws = (char*)d_ws;
    int* hist       = (int*)(ws);
    int* bin_start  = (int*)(ws + 16 * 1024);
    int* bin_cursor = (int*)(ws + 32 * 1024);
    int2* binned    = (int2*)(ws + BINNED_OFF);

    hipMemsetAsync(hist, 0, (size_t)nbins * sizeof(int), stream);

    hist_kernel<<<512, 256, 0, stream>>>(bidx + E, hist, E, nbins);
    scan_kernel<<<1, MAX_BINS, 0, stream>>>(hist, bin_start, bin_cursor, nbins);

    int cblocks = (E + CHUNK_C - 1) / CHUNK_C;
    binscatter_kernel<<<cblocks, 256, 0, stream>>>(bidx, bin_cursor, binned, E, nbins);

    bingather_kernel<<<nbins, 256, 0, stream>>>(
        (const float4*)x, bin_start, binned, (float4*)out, NOUT);
}